// Round 8
// baseline (1490.333 us; speedup 1.0000x reference)
//
#include <hip/hip_runtime.h>
#include <stdint.h>

#define DIM 128

static inline int cdiv(long a, long b) { return (int)((a + b - 1) / b); }

__device__ __forceinline__ unsigned short f2bf(float f) {
  unsigned int x = __float_as_uint(f);
  x = x + 0x7fffu + ((x >> 16) & 1u);   // RNE; values finite
  return (unsigned short)(x >> 16);
}
__device__ __forceinline__ float bflo(unsigned int u) {
  return __uint_as_float(u << 16);
}
__device__ __forceinline__ float bfhi(unsigned int u) {
  return __uint_as_float(u & 0xffff0000u);
}
__device__ __forceinline__ unsigned int packbf(float lo, float hi) {
  return ((unsigned int)f2bf(hi) << 16) | (unsigned int)f2bf(lo);
}

// ---- convert int64/int32 edge_index to int32 AND count degrees in one pass ----
__global__ __launch_bounds__(256) void convert_count_kernel(
    const int* __restrict__ raw, int* __restrict__ out, int* __restrict__ cnt,
    int E, long nnz) {
  bool is64;
  {
    int l = threadIdx.x & 63;
    int v = raw[2 * l + 1];
    unsigned long long m = __ballot(v == 0);
    is64 = (m == ~0ull);
  }
  long i = blockIdx.x * 256L + threadIdx.x;
  if (i < 2 * nnz) {
    int v = is64 ? raw[2 * i] : raw[i];
    out[i] = v;
    if (i < nnz) atomicAdd(&cnt[E + v], 1);   // src half -> node degree
    else         atomicAdd(&cnt[v], 1);       // edg half -> edge size
  }
}

// ---- 3-kernel exclusive scan of cnt[0..M) into P[0..M], P[M]=total ----
__global__ __launch_bounds__(256) void scanA_kernel(
    const int* __restrict__ cnt, int* __restrict__ P, int* __restrict__ BS, int M) {
  __shared__ int lds[256];
  int t = threadIdx.x;
  long base = blockIdx.x * 1024L;
  int v[4], ts = 0;
#pragma unroll
  for (int j = 0; j < 4; ++j) {
    long i = base + t * 4 + j;
    v[j] = (i < M) ? cnt[i] : 0;
    ts += v[j];
  }
  lds[t] = ts;
  __syncthreads();
  for (int off = 1; off < 256; off <<= 1) {
    int x = (t >= off) ? lds[t - off] : 0;
    __syncthreads();
    lds[t] += x;
    __syncthreads();
  }
  int run = lds[t] - ts;
#pragma unroll
  for (int j = 0; j < 4; ++j) {
    long i = base + t * 4 + j;
    if (i < M) P[i] = run;
    run += v[j];
  }
  if (t == 255) BS[blockIdx.x] = lds[255];
}

__global__ void scanB_kernel(int* __restrict__ BS, int* __restrict__ P,
                             int nblocks, int M) {
  if (threadIdx.x == 0) {
    int run = 0;
    for (int i = 0; i < nblocks; ++i) { int x = BS[i]; BS[i] = run; run += x; }
    P[M] = run;
  }
}

__global__ __launch_bounds__(256) void scanC_kernel(
    int* __restrict__ P, const int* __restrict__ BS, int M) {
  long i = blockIdx.x * 256L + threadIdx.x;
  if (i < M) P[i] += BS[i >> 10];
}

__global__ __launch_bounds__(256) void fill_adj_kernel(
    const int* __restrict__ src, const int* __restrict__ edg,
    const int* __restrict__ P, int* __restrict__ cnt,
    int* __restrict__ adj_e, int* __restrict__ adj_n, int E, int nnz) {
  int g = blockIdx.x * 256 + threadIdx.x;
  if (g < nnz) {
    int e = edg[g], s = src[g];
    int pe = P[e] + atomicAdd(&cnt[e], 1);
    adj_e[pe] = s;
    int pn = P[E + s] - nnz + atomicAdd(&cnt[E + s], 1);
    adj_n[pn] = e;
  }
}

// Wp = diag(a) @ W ; rvec = d @ W
__global__ void prep_w_kernel(const float* __restrict__ W,
                              const float* __restrict__ aff_a,
                              const float* __restrict__ aff_d,
                              float* __restrict__ Wp, float* __restrict__ rvec,
                              int has_aff) {
  int j = threadIdx.x;
  float racc = 0.0f;
  for (int c = 0; c < DIM; ++c) {
    float w = W[c * DIM + j];
    float a = has_aff ? aff_a[c] : 1.0f;
    float d = has_aff ? aff_d[c] : 0.0f;
    Wp[c * DIM + j] = a * w;
    racc = fmaf(d, w, racc);
  }
  rvec[j] = racc;
}

// ag[e][:] = Binv_e * sum X rows (fp32 input, layer 1).
// 32 lanes/edge (float4), 8 slots/block. Preload-8 indices -> 8 parallel row
// loads per batch (one latency round-trip instead of interleaved chains).
__global__ __launch_bounds__(256) void edge_gather_f32_kernel(
    const float* __restrict__ X, const int* __restrict__ P,
    const int* __restrict__ adj_e, float* __restrict__ ag, int E) {
  int slot = threadIdx.x >> 5;
  int l = threadIdx.x & 31;
  int e = blockIdx.x * 8 + slot;
  if (e >= E) return;
  int p0 = P[e], p1 = P[e + 1];
  const float4* X4 = (const float4*)X;
  float4 acc = {0.f, 0.f, 0.f, 0.f};
  int k = p0;
  for (; k + 7 < p1; k += 8) {
    int idx[8];
#pragma unroll
    for (int j = 0; j < 8; ++j) idx[j] = adj_e[k + j];
    float4 v[8];
#pragma unroll
    for (int j = 0; j < 8; ++j) v[j] = X4[(size_t)idx[j] * 32 + l];
#pragma unroll
    for (int j = 0; j < 8; ++j) {
      acc.x += v[j].x; acc.y += v[j].y; acc.z += v[j].z; acc.w += v[j].w;
    }
  }
  int rem = p1 - k;
  if (rem > 0) {
    int last = p1 - 1;
    int idx[8];
#pragma unroll
    for (int j = 0; j < 8; ++j) { int kk = k + j; idx[j] = adj_e[kk < p1 ? kk : last]; }
    float4 v[8];
#pragma unroll
    for (int j = 0; j < 8; ++j) v[j] = X4[(size_t)idx[j] * 32 + l];
#pragma unroll
    for (int j = 0; j < 8; ++j) {
      if (j < rem) {
        acc.x += v[j].x; acc.y += v[j].y; acc.z += v[j].z; acc.w += v[j].w;
      }
    }
  }
  float binv = (p1 > p0) ? 1.0f / (float)(p1 - p0) : 0.0f;
  acc.x *= binv; acc.y *= binv; acc.z *= binv; acc.w *= binv;
  ((float4*)ag)[(size_t)e * 32 + l] = acc;
}

// ag[e][:] = Binv_e * sum z rows (bf16 input, layers 2-3).
// 32 lanes/edge (uint2 = 4 channels), 8 slots/block, preload-8 batches.
__global__ __launch_bounds__(256) void edge_gather_bf16_kernel(
    const unsigned short* __restrict__ Z, const int* __restrict__ P,
    const int* __restrict__ adj_e, float* __restrict__ ag, int E) {
  int slot = threadIdx.x >> 5;
  int l = threadIdx.x & 31;
  int e = blockIdx.x * 8 + slot;
  if (e >= E) return;
  int p0 = P[e], p1 = P[e + 1];
  const uint2* Z2 = (const uint2*)Z;
  float a0 = 0.f, a1 = 0.f, a2 = 0.f, a3 = 0.f;
  int k = p0;
  for (; k + 7 < p1; k += 8) {
    int idx[8];
#pragma unroll
    for (int j = 0; j < 8; ++j) idx[j] = adj_e[k + j];
    uint2 v[8];
#pragma unroll
    for (int j = 0; j < 8; ++j) v[j] = Z2[(size_t)idx[j] * 32 + l];
#pragma unroll
    for (int j = 0; j < 8; ++j) {
      a0 += bflo(v[j].x); a1 += bfhi(v[j].x);
      a2 += bflo(v[j].y); a3 += bfhi(v[j].y);
    }
  }
  int rem = p1 - k;
  if (rem > 0) {
    int last = p1 - 1;
    int idx[8];
#pragma unroll
    for (int j = 0; j < 8; ++j) { int kk = k + j; idx[j] = adj_e[kk < p1 ? kk : last]; }
    uint2 v[8];
#pragma unroll
    for (int j = 0; j < 8; ++j) v[j] = Z2[(size_t)idx[j] * 32 + l];
#pragma unroll
    for (int j = 0; j < 8; ++j) {
      if (j < rem) {
        a0 += bflo(v[j].x); a1 += bfhi(v[j].x);
        a2 += bflo(v[j].y); a3 += bfhi(v[j].y);
      }
    }
  }
  float binv = (p1 > p0) ? 1.0f / (float)(p1 - p0) : 0.0f;
  ((float4*)ag)[(size_t)e * 32 + l] =
      (float4){a0 * binv, a1 * binv, a2 * binv, a3 * binv};
}

// ef[E x 128](fp32) = ag(fp32) @ Wp + rvec, zeroed for empty edges.
// In-place safe (ag == ef): block reads only its own rows; reads complete
// (barrier) before any store.
__global__ __launch_bounds__(256) void gemm128_kernel(
    const float* __restrict__ X, const float* __restrict__ Wp,
    const float* __restrict__ rvec, const int* __restrict__ Pdeg,
    float* __restrict__ Y, int nrows) {
  __shared__ float sW[32 * DIM];
  __shared__ float sX[DIM * 36];
  const int t = threadIdx.x;
  const int row0 = blockIdx.x * DIM;
  const int tx = t & 15, ty = t >> 4;
  const int col0 = tx * 8, lr0 = ty * 8;
  float acc[8][8];
#pragma unroll
  for (int i = 0; i < 8; ++i)
#pragma unroll
    for (int j = 0; j < 8; ++j) acc[i][j] = 0.0f;

  for (int kc = 0; kc < 4; ++kc) {
    __syncthreads();
    {
      const float4* W4 = (const float4*)(Wp + kc * 32 * DIM);
      float4* sW4 = (float4*)sW;
#pragma unroll
      for (int i = 0; i < 4; ++i) sW4[t + i * 256] = W4[t + i * 256];
    }
#pragma unroll
    for (int i = 0; i < 4; ++i) {
      int q = t + i * 256;
      int rr = q >> 3, kq = q & 7;
      int gr = row0 + rr; if (gr >= nrows) gr = nrows - 1;
      float4 v = *(const float4*)&X[(size_t)gr * DIM + kc * 32 + kq * 4];
      *(float4*)&sX[rr * 36 + kq * 4] = v;
    }
    __syncthreads();
    for (int kk = 0; kk < 32; ++kk) {
      float4 w0 = *(const float4*)&sW[kk * DIM + col0];
      float4 w1 = *(const float4*)&sW[kk * DIM + col0 + 4];
      float wv[8] = {w0.x, w0.y, w0.z, w0.w, w1.x, w1.y, w1.z, w1.w};
      float xv[8];
#pragma unroll
      for (int i = 0; i < 8; ++i) xv[i] = sX[(lr0 + i) * 36 + kk];
#pragma unroll
      for (int i = 0; i < 8; ++i)
#pragma unroll
        for (int j = 0; j < 8; ++j) acc[i][j] = fmaf(xv[i], wv[j], acc[i][j]);
    }
  }
  float4 r0 = *(const float4*)&rvec[col0];
  float4 r1 = *(const float4*)&rvec[col0 + 4];
#pragma unroll
  for (int i = 0; i < 8; ++i) {
    int gr = row0 + lr0 + i;
    if (gr < nrows) {
      float nz = (Pdeg[gr + 1] > Pdeg[gr]) ? 1.0f : 0.0f;  // empty edge -> 0
      float4 o0, o1;
      o0.x = (acc[i][0] + r0.x) * nz; o0.y = (acc[i][1] + r0.y) * nz;
      o0.z = (acc[i][2] + r0.z) * nz; o0.w = (acc[i][3] + r0.w) * nz;
      o1.x = (acc[i][4] + r1.x) * nz; o1.y = (acc[i][5] + r1.y) * nz;
      o1.z = (acc[i][6] + r1.z) * nz; o1.w = (acc[i][7] + r1.w) * nz;
      *(float4*)&Y[(size_t)gr * DIM + col0]     = o0;
      *(float4*)&Y[(size_t)gr * DIM + col0 + 4] = o1;
    }
  }
}

// z[i][:](bf16) = relu(Dinv_i * sum ef rows + b), fused BN stats.
// 32 lanes/node (float4 of fp32 ef), 8 slots/block. Preload-8 indices ->
// 8 parallel row loads (deg<=8 covers ~80% of nodes in one round-trip).
__global__ __launch_bounds__(256) void node_gather_kernel(
    const float* __restrict__ ef, const int* __restrict__ P,
    const int* __restrict__ adj_n, const float* __restrict__ b,
    unsigned short* __restrict__ z, float* __restrict__ sum,
    float* __restrict__ sumsq, int E, int N, int nnz) {
  __shared__ float lsum[DIM], lsumsq[DIM];
  int t = threadIdx.x;
  if (t < DIM) { lsum[t] = 0.f; lsumsq[t] = 0.f; }
  __syncthreads();
  int slot = t >> 5;
  int l = t & 31;
  int i = blockIdx.x * 8 + slot;
  const float4* ef4 = (const float4*)ef;
  float4 acc = {0.f, 0.f, 0.f, 0.f};
  int deg = 0;
  if (i < N) {
    int p0 = P[E + i] - nnz, p1 = P[E + i + 1] - nnz;
    deg = p1 - p0;
    if (deg > 0) {
      int last = p1 - 1;
      int idx[8];
#pragma unroll
      for (int j = 0; j < 8; ++j) { int kk = p0 + j; idx[j] = adj_n[kk < p1 ? kk : last]; }
      float4 v[8];
#pragma unroll
      for (int j = 0; j < 8; ++j) v[j] = ef4[(size_t)idx[j] * 32 + l];
#pragma unroll
      for (int j = 0; j < 8; ++j) {
        if (j < deg) {
          acc.x += v[j].x; acc.y += v[j].y; acc.z += v[j].z; acc.w += v[j].w;
        }
      }
      int k = p0 + 8;
      for (; k + 1 < p1; k += 2) {
        int e0 = adj_n[k], e1 = adj_n[k + 1];
        float4 x0 = ef4[(size_t)e0 * 32 + l];
        float4 x1 = ef4[(size_t)e1 * 32 + l];
        acc.x += x0.x + x1.x; acc.y += x0.y + x1.y;
        acc.z += x0.z + x1.z; acc.w += x0.w + x1.w;
      }
      if (k < p1) {
        float4 x0 = ef4[(size_t)adj_n[k] * 32 + l];
        acc.x += x0.x; acc.y += x0.y; acc.z += x0.z; acc.w += x0.w;
      }
    }
  }
  float4 s1 = {0.f, 0.f, 0.f, 0.f}, s2 = {0.f, 0.f, 0.f, 0.f};
  if (i < N) {
    float dinv = (deg > 0) ? 1.0f / (float)deg : 0.0f;
    float4 bc = ((const float4*)b)[l];
    float4 v;
    v.x = fmaxf(fmaf(dinv, acc.x, bc.x), 0.f);
    v.y = fmaxf(fmaf(dinv, acc.y, bc.y), 0.f);
    v.z = fmaxf(fmaf(dinv, acc.z, bc.z), 0.f);
    v.w = fmaxf(fmaf(dinv, acc.w, bc.w), 0.f);
    uint2 o;
    o.x = packbf(v.x, v.y);
    o.y = packbf(v.z, v.w);
    ((uint2*)z)[(size_t)i * 32 + l] = o;
    s1 = v;
    s2.x = v.x * v.x; s2.y = v.y * v.y; s2.z = v.z * v.z; s2.w = v.w * v.w;
  }
  // reduce the 2 slots within each wave (lane and lane+32 share channels)
  s1.x += __shfl_down(s1.x, 32); s1.y += __shfl_down(s1.y, 32);
  s1.z += __shfl_down(s1.z, 32); s1.w += __shfl_down(s1.w, 32);
  s2.x += __shfl_down(s2.x, 32); s2.y += __shfl_down(s2.y, 32);
  s2.z += __shfl_down(s2.z, 32); s2.w += __shfl_down(s2.w, 32);
  if ((t & 63) < 32) {
    int c0 = l * 4;
    atomicAdd(&lsum[c0 + 0], s1.x); atomicAdd(&lsum[c0 + 1], s1.y);
    atomicAdd(&lsum[c0 + 2], s1.z); atomicAdd(&lsum[c0 + 3], s1.w);
    atomicAdd(&lsumsq[c0 + 0], s2.x); atomicAdd(&lsumsq[c0 + 1], s2.y);
    atomicAdd(&lsumsq[c0 + 2], s2.z); atomicAdd(&lsumsq[c0 + 3], s2.w);
  }
  __syncthreads();
  if (t < DIM) {
    atomicAdd(&sum[t], lsum[t]);
    atomicAdd(&sumsq[t], lsumsq[t]);
  }
}

// aff_a = g*rsqrt(var+eps); aff_d = beta - mu*aff_a
__global__ void finalize_bn_kernel(const float* __restrict__ sum,
                                   const float* __restrict__ sumsq,
                                   const float* __restrict__ g,
                                   const float* __restrict__ beta,
                                   float* __restrict__ aff_a, float* __restrict__ aff_d,
                                   int n) {
  int c = threadIdx.x;
  float inv_n = 1.0f / (float)n;
  float mu = sum[c] * inv_n;
  float var = fmaf(sumsq[c], inv_n, -mu * mu);
  float a = g[c] * rsqrtf(var + 1e-5f);
  aff_a[c] = a;
  aff_d[c] = fmaf(-mu, a, beta[c]);
}

// out(fp32) = aff_a * z(bf16) + aff_d; 8 channels per thread
__global__ __launch_bounds__(256) void apply_affine_kernel(
    const unsigned short* __restrict__ zin, const float* __restrict__ aff_a,
    const float* __restrict__ aff_d, float* __restrict__ out, long total8) {
  long i = blockIdx.x * 256L + threadIdx.x;
  if (i >= total8) return;
  int c16 = (int)(i & 15);
  const float4* a4 = (const float4*)aff_a + c16 * 2;
  const float4* d4 = (const float4*)aff_d + c16 * 2;
  float4 a0 = a4[0], a1 = a4[1], d0 = d4[0], d1 = d4[1];
  uint4 q = ((const uint4*)zin)[i];
  float4 o0, o1;
  o0.x = fmaf(a0.x, bflo(q.x), d0.x);
  o0.y = fmaf(a0.y, bfhi(q.x), d0.y);
  o0.z = fmaf(a0.z, bflo(q.y), d0.z);
  o0.w = fmaf(a0.w, bfhi(q.y), d0.w);
  o1.x = fmaf(a1.x, bflo(q.z), d1.x);
  o1.y = fmaf(a1.y, bfhi(q.z), d1.y);
  o1.z = fmaf(a1.z, bflo(q.w), d1.z);
  o1.w = fmaf(a1.w, bfhi(q.w), d1.w);
  ((float4*)out)[i * 2]     = o0;
  ((float4*)out)[i * 2 + 1] = o1;
}

extern "C" void kernel_launch(void* const* d_in, const int* in_sizes, int n_in,
                              void* d_out, int out_size, void* d_ws, size_t ws_size,
                              hipStream_t stream) {
  const int NNZv = in_sizes[0] / 2;
  const int Nv   = in_sizes[1] / DIM;
  const int Ev   = in_sizes[2] / DIM;
  const int* eidx_raw = (const int*)d_in[0];
  const float* node_attr = (const float*)d_in[1];

  // ---- workspace layout (~48 MB) ----
  float* agbuf = (float*)d_ws;                 // E*128 f32 (ag, then ef in-place)
  float* Wp    = agbuf + (size_t)Ev * DIM;     // 128*128
  float* rvec  = Wp + DIM * DIM;               // 128
  float* sums  = rvec + 128;                   // 128
  float* sumsq = sums + 128;                   // 128
  float* aff_a = sumsq + 128;                  // 128
  float* aff_d = aff_a + 128;                  // 128
  unsigned short* zbuf = (unsigned short*)(aff_d + 128);   // N*128 bf16
  int* src   = (int*)(zbuf + (size_t)Nv * DIM);  // NNZ
  int* edg   = src + NNZv;                       // NNZ
  int* P     = edg + NNZv;                       // E+N+1
  int* BS    = P + (Ev + Nv + 1);                // <=256
  int* cnt   = BS + 256;                         // E+N
  int* adj_e = cnt + (Ev + Nv);                  // NNZ
  int* adj_n = adj_e + NNZv;                     // NNZ

  const int M = Ev + Nv;
  const int nbA = cdiv(M, 1024);

  hipMemsetAsync(cnt, 0, (size_t)M * 4, stream);
  convert_count_kernel<<<cdiv(2L * NNZv, 256), 256, 0, stream>>>(
      eidx_raw, src, cnt, Ev, NNZv);
  scanA_kernel<<<nbA, 256, 0, stream>>>(cnt, P, BS, M);
  scanB_kernel<<<1, 64, 0, stream>>>(BS, P, nbA, M);
  scanC_kernel<<<cdiv(M, 256), 256, 0, stream>>>(P, BS, M);
  hipMemsetAsync(cnt, 0, (size_t)M * 4, stream);
  fill_adj_kernel<<<cdiv(NNZv, 256), 256, 0, stream>>>(src, edg, P, cnt, adj_e, adj_n, Ev, NNZv);

  for (int l = 0; l < 3; ++l) {
    const float* W    = (const float*)d_in[3 + l * 4];
    const float* b    = (const float*)d_in[4 + l * 4];
    const float* g    = (const float*)d_in[5 + l * 4];
    const float* beta = (const float*)d_in[6 + l * 4];

    prep_w_kernel<<<1, 128, 0, stream>>>(W, aff_a, aff_d, Wp, rvec, l > 0 ? 1 : 0);
    if (l == 0)
      edge_gather_f32_kernel<<<cdiv(Ev, 8), 256, 0, stream>>>(node_attr, P, adj_e, agbuf, Ev);
    else
      edge_gather_bf16_kernel<<<cdiv(Ev, 8), 256, 0, stream>>>(zbuf, P, adj_e, agbuf, Ev);
    gemm128_kernel<<<cdiv(Ev, DIM), 256, 0, stream>>>(agbuf, Wp, rvec, P, agbuf, Ev);
    hipMemsetAsync(sums, 0, 256 * 4, stream);
    node_gather_kernel<<<cdiv(Nv, 8), 256, 0, stream>>>(agbuf, P, adj_n, b, zbuf,
                                                        sums, sumsq, Ev, Nv, NNZv);
    finalize_bn_kernel<<<1, 128, 0, stream>>>(sums, sumsq, g, beta, aff_a, aff_d, Nv);
  }
  apply_affine_kernel<<<cdiv((long)Nv * DIM / 8, 256), 256, 0, stream>>>(
      zbuf, aff_a, aff_d, (float*)d_out, (long)Nv * DIM / 8);
}

// Round 9
// 1049.960 us; speedup vs baseline: 1.4194x; 1.4194x over previous
//
#include <hip/hip_runtime.h>
#include <stdint.h>

#define DIM 128

static inline int cdiv(long a, long b) { return (int)((a + b - 1) / b); }

__device__ __forceinline__ unsigned short f2bf(float f) {
  unsigned int x = __float_as_uint(f);
  x = x + 0x7fffu + ((x >> 16) & 1u);   // RNE; values finite
  return (unsigned short)(x >> 16);
}
__device__ __forceinline__ float bflo(unsigned int u) {
  return __uint_as_float(u << 16);
}
__device__ __forceinline__ float bfhi(unsigned int u) {
  return __uint_as_float(u & 0xffff0000u);
}
__device__ __forceinline__ unsigned int packbf(float lo, float hi) {
  return ((unsigned int)f2bf(hi) << 16) | (unsigned int)f2bf(lo);
}

// ---- convert int64/int32 edge_index to int32 AND count degrees in one pass ----
__global__ __launch_bounds__(256) void convert_count_kernel(
    const int* __restrict__ raw, int* __restrict__ out, int* __restrict__ cnt,
    int E, long nnz) {
  bool is64;
  {
    int l = threadIdx.x & 63;
    int v = raw[2 * l + 1];
    unsigned long long m = __ballot(v == 0);
    is64 = (m == ~0ull);
  }
  long i = blockIdx.x * 256L + threadIdx.x;
  if (i < 2 * nnz) {
    int v = is64 ? raw[2 * i] : raw[i];
    out[i] = v;
    if (i < nnz) atomicAdd(&cnt[E + v], 1);   // src half -> node degree
    else         atomicAdd(&cnt[v], 1);       // edg half -> edge size
  }
}

// ---- 3-kernel exclusive scan of cnt[0..M) into P[0..M], P[M]=total ----
__global__ __launch_bounds__(256) void scanA_kernel(
    const int* __restrict__ cnt, int* __restrict__ P, int* __restrict__ BS, int M) {
  __shared__ int lds[256];
  int t = threadIdx.x;
  long base = blockIdx.x * 1024L;
  int v[4], ts = 0;
#pragma unroll
  for (int j = 0; j < 4; ++j) {
    long i = base + t * 4 + j;
    v[j] = (i < M) ? cnt[i] : 0;
    ts += v[j];
  }
  lds[t] = ts;
  __syncthreads();
  for (int off = 1; off < 256; off <<= 1) {
    int x = (t >= off) ? lds[t - off] : 0;
    __syncthreads();
    lds[t] += x;
    __syncthreads();
  }
  int run = lds[t] - ts;
#pragma unroll
  for (int j = 0; j < 4; ++j) {
    long i = base + t * 4 + j;
    if (i < M) P[i] = run;
    run += v[j];
  }
  if (t == 255) BS[blockIdx.x] = lds[255];
}

__global__ void scanB_kernel(int* __restrict__ BS, int* __restrict__ P,
                             int nblocks, int M) {
  if (threadIdx.x == 0) {
    int run = 0;
    for (int i = 0; i < nblocks; ++i) { int x = BS[i]; BS[i] = run; run += x; }
    P[M] = run;
  }
}

__global__ __launch_bounds__(256) void scanC_kernel(
    int* __restrict__ P, const int* __restrict__ BS, int M) {
  long i = blockIdx.x * 256L + threadIdx.x;
  if (i < M) P[i] += BS[i >> 10];
}

__global__ __launch_bounds__(256) void fill_adj_kernel(
    const int* __restrict__ src, const int* __restrict__ edg,
    const int* __restrict__ P, int* __restrict__ cnt,
    int* __restrict__ adj_e, int* __restrict__ adj_n, int E, int nnz) {
  int g = blockIdx.x * 256 + threadIdx.x;
  if (g < nnz) {
    int e = edg[g], s = src[g];
    int pe = P[e] + atomicAdd(&cnt[e], 1);
    adj_e[pe] = s;
    int pn = P[E + s] - nnz + atomicAdd(&cnt[E + s], 1);
    adj_n[pn] = e;
  }
}

// Wp = diag(a) @ W ; rvec = d @ W
__global__ void prep_w_kernel(const float* __restrict__ W,
                              const float* __restrict__ aff_a,
                              const float* __restrict__ aff_d,
                              float* __restrict__ Wp, float* __restrict__ rvec,
                              int has_aff) {
  int j = threadIdx.x;
  float racc = 0.0f;
  for (int c = 0; c < DIM; ++c) {
    float w = W[c * DIM + j];
    float a = has_aff ? aff_a[c] : 1.0f;
    float d = has_aff ? aff_d[c] : 0.0f;
    Wp[c * DIM + j] = a * w;
    racc = fmaf(d, w, racc);
  }
  rvec[j] = racc;
}

// ag[e][:] = Binv_e * sum X rows (fp32). 16 lanes/edge, 2 float4 segs, unroll 4.
// (Round-5 proven geometry.)
__global__ __launch_bounds__(256) void edge_gather_kernel(
    const float* __restrict__ X, const int* __restrict__ P,
    const int* __restrict__ adj_e, float* __restrict__ ag, int E) {
  int slot = threadIdx.x >> 4;
  int l = threadIdx.x & 15;
  int e = blockIdx.x * 16 + slot;
  if (e >= E) return;
  int p0 = P[e], p1 = P[e + 1];
  const float4* X4 = (const float4*)X;
  float4 a0 = {0.f, 0.f, 0.f, 0.f}, a1 = {0.f, 0.f, 0.f, 0.f};
  int k = p0;
  for (; k + 3 < p1; k += 4) {
    int n0 = adj_e[k], n1 = adj_e[k + 1], n2 = adj_e[k + 2], n3 = adj_e[k + 3];
    const float4* r0 = &X4[(size_t)n0 * 32];
    const float4* r1 = &X4[(size_t)n1 * 32];
    const float4* r2 = &X4[(size_t)n2 * 32];
    const float4* r3 = &X4[(size_t)n3 * 32];
    float4 x00 = r0[l], x01 = r0[l + 16];
    float4 x10 = r1[l], x11 = r1[l + 16];
    float4 x20 = r2[l], x21 = r2[l + 16];
    float4 x30 = r3[l], x31 = r3[l + 16];
    a0.x += (x00.x + x10.x) + (x20.x + x30.x);
    a0.y += (x00.y + x10.y) + (x20.y + x30.y);
    a0.z += (x00.z + x10.z) + (x20.z + x30.z);
    a0.w += (x00.w + x10.w) + (x20.w + x30.w);
    a1.x += (x01.x + x11.x) + (x21.x + x31.x);
    a1.y += (x01.y + x11.y) + (x21.y + x31.y);
    a1.z += (x01.z + x11.z) + (x21.z + x31.z);
    a1.w += (x01.w + x11.w) + (x21.w + x31.w);
  }
  for (; k < p1; ++k) {
    const float4* r0 = &X4[(size_t)adj_e[k] * 32];
    float4 x00 = r0[l], x01 = r0[l + 16];
    a0.x += x00.x; a0.y += x00.y; a0.z += x00.z; a0.w += x00.w;
    a1.x += x01.x; a1.y += x01.y; a1.z += x01.z; a1.w += x01.w;
  }
  float binv = (p1 > p0) ? 1.0f / (float)(p1 - p0) : 0.0f;
  a0.x *= binv; a0.y *= binv; a0.z *= binv; a0.w *= binv;
  a1.x *= binv; a1.y *= binv; a1.z *= binv; a1.w *= binv;
  float4* o = (float4*)ag + (size_t)e * 32;
  o[l] = a0;
  o[l + 16] = a1;
}

// ef(fp32, in-place over ag) AND ef16(bf16 copy) = ag @ Wp + rvec; 0 for empty edges.
__global__ __launch_bounds__(256) void gemm128_kernel(
    const float* __restrict__ X, const float* __restrict__ Wp,
    const float* __restrict__ rvec, const int* __restrict__ Pdeg,
    float* __restrict__ Y, unsigned short* __restrict__ Y16, int nrows) {
  __shared__ float sW[32 * DIM];
  __shared__ float sX[DIM * 36];
  const int t = threadIdx.x;
  const int row0 = blockIdx.x * DIM;
  const int tx = t & 15, ty = t >> 4;
  const int col0 = tx * 8, lr0 = ty * 8;
  float acc[8][8];
#pragma unroll
  for (int i = 0; i < 8; ++i)
#pragma unroll
    for (int j = 0; j < 8; ++j) acc[i][j] = 0.0f;

  for (int kc = 0; kc < 4; ++kc) {
    __syncthreads();
    {
      const float4* W4 = (const float4*)(Wp + kc * 32 * DIM);
      float4* sW4 = (float4*)sW;
#pragma unroll
      for (int i = 0; i < 4; ++i) sW4[t + i * 256] = W4[t + i * 256];
    }
#pragma unroll
    for (int i = 0; i < 4; ++i) {
      int q = t + i * 256;
      int rr = q >> 3, kq = q & 7;
      int gr = row0 + rr; if (gr >= nrows) gr = nrows - 1;
      float4 v = *(const float4*)&X[(size_t)gr * DIM + kc * 32 + kq * 4];
      *(float4*)&sX[rr * 36 + kq * 4] = v;
    }
    __syncthreads();
    for (int kk = 0; kk < 32; ++kk) {
      float4 w0 = *(const float4*)&sW[kk * DIM + col0];
      float4 w1 = *(const float4*)&sW[kk * DIM + col0 + 4];
      float wv[8] = {w0.x, w0.y, w0.z, w0.w, w1.x, w1.y, w1.z, w1.w};
      float xv[8];
#pragma unroll
      for (int i = 0; i < 8; ++i) xv[i] = sX[(lr0 + i) * 36 + kk];
#pragma unroll
      for (int i = 0; i < 8; ++i)
#pragma unroll
        for (int j = 0; j < 8; ++j) acc[i][j] = fmaf(xv[i], wv[j], acc[i][j]);
    }
  }
  float4 r0 = *(const float4*)&rvec[col0];
  float4 r1 = *(const float4*)&rvec[col0 + 4];
#pragma unroll
  for (int i = 0; i < 8; ++i) {
    int gr = row0 + lr0 + i;
    if (gr < nrows) {
      float nz = (Pdeg[gr + 1] > Pdeg[gr]) ? 1.0f : 0.0f;  // empty edge -> 0
      float4 o0, o1;
      o0.x = (acc[i][0] + r0.x) * nz; o0.y = (acc[i][1] + r0.y) * nz;
      o0.z = (acc[i][2] + r0.z) * nz; o0.w = (acc[i][3] + r0.w) * nz;
      o1.x = (acc[i][4] + r1.x) * nz; o1.y = (acc[i][5] + r1.y) * nz;
      o1.z = (acc[i][6] + r1.z) * nz; o1.w = (acc[i][7] + r1.w) * nz;
      *(float4*)&Y[(size_t)gr * DIM + col0]     = o0;
      *(float4*)&Y[(size_t)gr * DIM + col0 + 4] = o1;
      uint4 p;
      p.x = packbf(o0.x, o0.y); p.y = packbf(o0.z, o0.w);
      p.z = packbf(o1.x, o1.y); p.w = packbf(o1.z, o1.w);
      ((uint4*)Y16)[(size_t)gr * 16 + tx] = p;
    }
  }
}

#define NG_EPILOGUE_32(ACC)                                            \
  float4 s1 = {0.f, 0.f, 0.f, 0.f}, s2 = {0.f, 0.f, 0.f, 0.f};        \
  {                                                                    \
    float dinv = (p1 > p0) ? 1.0f / (float)(p1 - p0) : 0.0f;           \
    float4 bc = ((const float4*)b)[l];                                 \
    float4 v;                                                          \
    v.x = fmaxf(fmaf(dinv, ACC.x, bc.x), 0.f);                         \
    v.y = fmaxf(fmaf(dinv, ACC.y, bc.y), 0.f);                         \
    v.z = fmaxf(fmaf(dinv, ACC.z, bc.z), 0.f);                         \
    v.w = fmaxf(fmaf(dinv, ACC.w, bc.w), 0.f);                         \
    ((float4*)z)[(size_t)i * 32 + l] = v;                              \
    s1 = v;                                                            \
    s2.x = v.x * v.x; s2.y = v.y * v.y;                                \
    s2.z = v.z * v.z; s2.w = v.w * v.w;                                \
  }                                                                    \
  int c0 = l * 4;                                                      \
  atomicAdd(&lsum[c0 + 0], s1.x); atomicAdd(&lsum[c0 + 1], s1.y);      \
  atomicAdd(&lsum[c0 + 2], s1.z); atomicAdd(&lsum[c0 + 3], s1.w);      \
  atomicAdd(&lsumsq[c0 + 0], s2.x); atomicAdd(&lsumsq[c0 + 1], s2.y);  \
  atomicAdd(&lsumsq[c0 + 2], s2.z); atomicAdd(&lsumsq[c0 + 3], s2.w);

// V0 (control): fp32 ef, 32-lane slots, unroll-4 + tail. Round-5 exact.
__global__ __launch_bounds__(256) void node_gather_f32_kernel(
    const float* __restrict__ ef, const int* __restrict__ P,
    const int* __restrict__ adj_n, const float* __restrict__ b,
    float* __restrict__ z, float* __restrict__ sum,
    float* __restrict__ sumsq, int E, int N, int nnz) {
  __shared__ float lsum[DIM], lsumsq[DIM];
  int t = threadIdx.x;
  if (t < DIM) { lsum[t] = 0.f; lsumsq[t] = 0.f; }
  __syncthreads();
  int slot = t >> 5;
  int l = t & 31;
  const float4* ef4 = (const float4*)ef;
  for (int i = blockIdx.x * 8 + slot; i < N; i += gridDim.x * 8) {
    int p0 = P[E + i] - nnz, p1 = P[E + i + 1] - nnz;
    float4 acc = {0.f, 0.f, 0.f, 0.f};
    int k = p0;
    for (; k + 3 < p1; k += 4) {
      int e0 = adj_n[k], e1 = adj_n[k + 1], e2 = adj_n[k + 2], e3 = adj_n[k + 3];
      float4 x0 = ef4[(size_t)e0 * 32 + l];
      float4 x1 = ef4[(size_t)e1 * 32 + l];
      float4 x2 = ef4[(size_t)e2 * 32 + l];
      float4 x3 = ef4[(size_t)e3 * 32 + l];
      acc.x += (x0.x + x1.x) + (x2.x + x3.x);
      acc.y += (x0.y + x1.y) + (x2.y + x3.y);
      acc.z += (x0.z + x1.z) + (x2.z + x3.z);
      acc.w += (x0.w + x1.w) + (x2.w + x3.w);
    }
    for (; k < p1; ++k) {
      float4 x0 = ef4[(size_t)adj_n[k] * 32 + l];
      acc.x += x0.x; acc.y += x0.y; acc.z += x0.z; acc.w += x0.w;
    }
    NG_EPILOGUE_32(acc)
  }
  __syncthreads();
  if (t < DIM) {
    atomicAdd(&sum[t], lsum[t]);
    atomicAdd(&sumsq[t], lsumsq[t]);
  }
}

// V1: bf16 ef, 32-lane slots (uint2 = 4 ch/lane), unroll-4 + tail.
__global__ __launch_bounds__(256) void node_gather_bf16a_kernel(
    const unsigned short* __restrict__ ef16, const int* __restrict__ P,
    const int* __restrict__ adj_n, const float* __restrict__ b,
    float* __restrict__ z, float* __restrict__ sum,
    float* __restrict__ sumsq, int E, int N, int nnz) {
  __shared__ float lsum[DIM], lsumsq[DIM];
  int t = threadIdx.x;
  if (t < DIM) { lsum[t] = 0.f; lsumsq[t] = 0.f; }
  __syncthreads();
  int slot = t >> 5;
  int l = t & 31;
  const uint2* E2 = (const uint2*)ef16;
  for (int i = blockIdx.x * 8 + slot; i < N; i += gridDim.x * 8) {
    int p0 = P[E + i] - nnz, p1 = P[E + i + 1] - nnz;
    float4 acc = {0.f, 0.f, 0.f, 0.f};
    int k = p0;
    for (; k + 3 < p1; k += 4) {
      int e0 = adj_n[k], e1 = adj_n[k + 1], e2 = adj_n[k + 2], e3 = adj_n[k + 3];
      uint2 q0 = E2[(size_t)e0 * 32 + l];
      uint2 q1 = E2[(size_t)e1 * 32 + l];
      uint2 q2 = E2[(size_t)e2 * 32 + l];
      uint2 q3 = E2[(size_t)e3 * 32 + l];
      acc.x += (bflo(q0.x) + bflo(q1.x)) + (bflo(q2.x) + bflo(q3.x));
      acc.y += (bfhi(q0.x) + bfhi(q1.x)) + (bfhi(q2.x) + bfhi(q3.x));
      acc.z += (bflo(q0.y) + bflo(q1.y)) + (bflo(q2.y) + bflo(q3.y));
      acc.w += (bfhi(q0.y) + bfhi(q1.y)) + (bfhi(q2.y) + bfhi(q3.y));
    }
    for (; k < p1; ++k) {
      uint2 q0 = E2[(size_t)adj_n[k] * 32 + l];
      acc.x += bflo(q0.x); acc.y += bfhi(q0.x);
      acc.z += bflo(q0.y); acc.w += bfhi(q0.y);
    }
    NG_EPILOGUE_32(acc)
  }
  __syncthreads();
  if (t < DIM) {
    atomicAdd(&sum[t], lsum[t]);
    atomicAdd(&sumsq[t], lsumsq[t]);
  }
}

// V2: bf16 ef, 16-lane slots (uint4 = 8 ch/lane), unroll-4 + tail.
__global__ __launch_bounds__(256) void node_gather_bf16b_kernel(
    const unsigned short* __restrict__ ef16, const int* __restrict__ P,
    const int* __restrict__ adj_n, const float* __restrict__ b,
    float* __restrict__ z, float* __restrict__ sum,
    float* __restrict__ sumsq, int E, int N, int nnz) {
  __shared__ float lsum[DIM], lsumsq[DIM];
  int t = threadIdx.x;
  if (t < DIM) { lsum[t] = 0.f; lsumsq[t] = 0.f; }
  __syncthreads();
  int slot = t >> 4;
  int l = t & 15;
  const uint4* E4 = (const uint4*)ef16;
  for (int i = blockIdx.x * 16 + slot; i < N; i += gridDim.x * 16) {
    int p0 = P[E + i] - nnz, p1 = P[E + i + 1] - nnz;
    float a[8];
#pragma unroll
    for (int j = 0; j < 8; ++j) a[j] = 0.f;
    int k = p0;
    for (; k + 3 < p1; k += 4) {
      int e0 = adj_n[k], e1 = adj_n[k + 1], e2 = adj_n[k + 2], e3 = adj_n[k + 3];
      uint4 q0 = E4[(size_t)e0 * 16 + l];
      uint4 q1 = E4[(size_t)e1 * 16 + l];
      uint4 q2 = E4[(size_t)e2 * 16 + l];
      uint4 q3 = E4[(size_t)e3 * 16 + l];
      a[0] += (bflo(q0.x) + bflo(q1.x)) + (bflo(q2.x) + bflo(q3.x));
      a[1] += (bfhi(q0.x) + bfhi(q1.x)) + (bfhi(q2.x) + bfhi(q3.x));
      a[2] += (bflo(q0.y) + bflo(q1.y)) + (bflo(q2.y) + bflo(q3.y));
      a[3] += (bfhi(q0.y) + bfhi(q1.y)) + (bfhi(q2.y) + bfhi(q3.y));
      a[4] += (bflo(q0.z) + bflo(q1.z)) + (bflo(q2.z) + bflo(q3.z));
      a[5] += (bfhi(q0.z) + bfhi(q1.z)) + (bfhi(q2.z) + bfhi(q3.z));
      a[6] += (bflo(q0.w) + bflo(q1.w)) + (bflo(q2.w) + bflo(q3.w));
      a[7] += (bfhi(q0.w) + bfhi(q1.w)) + (bfhi(q2.w) + bfhi(q3.w));
    }
    for (; k < p1; ++k) {
      uint4 q0 = E4[(size_t)adj_n[k] * 16 + l];
      a[0] += bflo(q0.x); a[1] += bfhi(q0.x);
      a[2] += bflo(q0.y); a[3] += bfhi(q0.y);
      a[4] += bflo(q0.z); a[5] += bfhi(q0.z);
      a[6] += bflo(q0.w); a[7] += bfhi(q0.w);
    }
    float dinv = (p1 > p0) ? 1.0f / (float)(p1 - p0) : 0.0f;
    const float4* b4 = (const float4*)b + l * 2;
    float4 bc0 = b4[0], bc1 = b4[1];
    float bc[8] = {bc0.x, bc0.y, bc0.z, bc0.w, bc1.x, bc1.y, bc1.z, bc1.w};
    float v[8];
#pragma unroll
    for (int j = 0; j < 8; ++j) v[j] = fmaxf(fmaf(dinv, a[j], bc[j]), 0.f);
    float4 o0 = {v[0], v[1], v[2], v[3]}, o1 = {v[4], v[5], v[6], v[7]};
    float4* z4 = (float4*)z + (size_t)i * 32 + l * 2;
    z4[0] = o0; z4[1] = o1;
#pragma unroll
    for (int j = 0; j < 8; ++j) {
      atomicAdd(&lsum[l * 8 + j], v[j]);
      atomicAdd(&lsumsq[l * 8 + j], v[j] * v[j]);
    }
  }
  __syncthreads();
  if (t < DIM) {
    atomicAdd(&sum[t], lsum[t]);
    atomicAdd(&sumsq[t], lsumsq[t]);
  }
}

// aff_a = g*rsqrt(var+eps); aff_d = beta - mu*aff_a
__global__ void finalize_bn_kernel(const float* __restrict__ sum,
                                   const float* __restrict__ sumsq,
                                   const float* __restrict__ g,
                                   const float* __restrict__ beta,
                                   float* __restrict__ aff_a, float* __restrict__ aff_d,
                                   int n) {
  int c = threadIdx.x;
  float inv_n = 1.0f / (float)n;
  float mu = sum[c] * inv_n;
  float var = fmaf(sumsq[c], inv_n, -mu * mu);
  float a = g[c] * rsqrtf(var + 1e-5f);
  aff_a[c] = a;
  aff_d[c] = fmaf(-mu, a, beta[c]);
}

// out = aff_a*z + aff_d (fp32, in-place safe: pure elementwise)
__global__ __launch_bounds__(256) void apply_affine_kernel(
    const float* __restrict__ zin, const float* __restrict__ aff_a,
    const float* __restrict__ aff_d, float* __restrict__ out, long total4) {
  long i = blockIdx.x * 256L + threadIdx.x;
  if (i >= total4) return;
  int c4 = (int)(i & 31);
  float4 a = ((const float4*)aff_a)[c4];
  float4 d = ((const float4*)aff_d)[c4];
  float4 v = ((const float4*)zin)[i];
  float4 o;
  o.x = fmaf(a.x, v.x, d.x);
  o.y = fmaf(a.y, v.y, d.y);
  o.z = fmaf(a.z, v.z, d.z);
  o.w = fmaf(a.w, v.w, d.w);
  ((float4*)out)[i] = o;
}

extern "C" void kernel_launch(void* const* d_in, const int* in_sizes, int n_in,
                              void* d_out, int out_size, void* d_ws, size_t ws_size,
                              hipStream_t stream) {
  const int NNZv = in_sizes[0] / 2;
  const int Nv   = in_sizes[1] / DIM;
  const int Ev   = in_sizes[2] / DIM;
  const int* eidx_raw = (const int*)d_in[0];
  const float* node_attr = (const float*)d_in[1];

  // ---- workspace layout (~31 MB) ----
  float* agbuf = (float*)d_ws;                 // E*128 f32 (ag, then ef in-place)
  float* Wp    = agbuf + (size_t)Ev * DIM;     // 128*128
  float* rvec  = Wp + DIM * DIM;               // 128
  float* sums  = rvec + 128;                   // 128
  float* sumsq = sums + 128;                   // 128
  float* aff_a = sumsq + 128;                  // 128
  float* aff_d = aff_a + 128;                  // 128
  unsigned short* ef16 = (unsigned short*)(aff_d + 128);   // E*128 bf16
  int* src   = (int*)(ef16 + (size_t)Ev * DIM);  // NNZ
  int* edg   = src + NNZv;                       // NNZ
  int* P     = edg + NNZv;                       // E+N+1
  int* BS    = P + (Ev + Nv + 1);                // <=256
  int* cnt   = BS + 256;                         // E+N
  int* adj_e = cnt + (Ev + Nv);                  // NNZ
  int* adj_n = adj_e + NNZv;                     // NNZ
  float* Ybuf = (float*)d_out;                   // z time-shares d_out (fp32)

  const int M = Ev + Nv;
  const int nbA = cdiv(M, 1024);

  hipMemsetAsync(cnt, 0, (size_t)M * 4, stream);
  convert_count_kernel<<<cdiv(2L * NNZv, 256), 256, 0, stream>>>(
      eidx_raw, src, cnt, Ev, NNZv);
  scanA_kernel<<<nbA, 256, 0, stream>>>(cnt, P, BS, M);
  scanB_kernel<<<1, 64, 0, stream>>>(BS, P, nbA, M);
  scanC_kernel<<<cdiv(M, 256), 256, 0, stream>>>(P, BS, M);
  hipMemsetAsync(cnt, 0, (size_t)M * 4, stream);
  fill_adj_kernel<<<cdiv(NNZv, 256), 256, 0, stream>>>(src, edg, P, cnt, adj_e, adj_n, Ev, NNZv);

  const float* Xin = node_attr;
  for (int l = 0; l < 3; ++l) {
    const float* W    = (const float*)d_in[3 + l * 4];
    const float* b    = (const float*)d_in[4 + l * 4];
    const float* g    = (const float*)d_in[5 + l * 4];
    const float* beta = (const float*)d_in[6 + l * 4];

    prep_w_kernel<<<1, 128, 0, stream>>>(W, aff_a, aff_d, Wp, rvec, l > 0 ? 1 : 0);
    edge_gather_kernel<<<cdiv(Ev, 16), 256, 0, stream>>>(Xin, P, adj_e, agbuf, Ev);
    gemm128_kernel<<<cdiv(Ev, DIM), 256, 0, stream>>>(agbuf, Wp, rvec, P, agbuf, ef16, Ev);
    hipMemsetAsync(sums, 0, 256 * 4, stream);
    // A/B/C experiment: layer 0 = fp32 control; layer 1 = bf16 32-lane;
    // layer 2 = bf16 16-lane. Compare per-dispatch dur in rocprof.
    if (l == 0)
      node_gather_f32_kernel<<<2048, 256, 0, stream>>>(agbuf, P, adj_n, b, Ybuf,
                                                       sums, sumsq, Ev, Nv, NNZv);
    else if (l == 1)
      node_gather_bf16a_kernel<<<2048, 256, 0, stream>>>(ef16, P, adj_n, b, Ybuf,
                                                         sums, sumsq, Ev, Nv, NNZv);
    else
      node_gather_bf16b_kernel<<<2048, 256, 0, stream>>>(ef16, P, adj_n, b, Ybuf,
                                                         sums, sumsq, Ev, Nv, NNZv);
    finalize_bn_kernel<<<1, 128, 0, stream>>>(sums, sumsq, g, beta, aff_a, aff_d, Nv);
    Xin = Ybuf;
  }
  apply_affine_kernel<<<cdiv((long)Nv * DIM / 4, 256), 256, 0, stream>>>(
      Ybuf, aff_a, aff_d, (float*)d_out, (long)Nv * DIM / 4);
}